// Round 7
// baseline (75.774 us; speedup 1.0000x reference)
//
#include <hip/hip_runtime.h>
#include <math.h>

// Problem constants
#define NB 4
#define BINS 256
#define HW (512*512)

// Decomposition: 256 blocks x 1024 threads (16 waves/CU for latency hiding).
#define CHUNKS 64
#define PIX_PER_BLOCK (HW / CHUNKS)     // 4096 = 1024 threads * 1 float4
#define HIST_BLOCKS (NB * CHUNKS)       // 256
#define THREADS 1024

// Truncated correlation support d in [-64, 63]: 128 taps = 4 groups x 32.
// Tail kernel mass ~1.0e-3 -> ~4e-5 abs output error vs 9.4e-4 threshold.
#define M_LO 64
#define GTAPS 32
#define HSP (M_LO + BINS + 64)          // 384 padded histogram entries

// ws layout: ctrl[64] uint (zeroed by async memset each launch) | Hp[256*256] uint
// ctrl: [0..3]=per-batch arrival counters, [4]=finish counter, [5]=entropy acc (f32)

__global__ __launch_bounds__(THREADS) void fused_entropy(
        const float* __restrict__ y,
        unsigned* __restrict__ Hp,
        unsigned* __restrict__ ctrl,
        float* __restrict__ out) {
    __shared__ unsigned lh[BINS];
    __shared__ float Hs4[4][BINS];      // group partials, reused for conv partials
    __shared__ float Hs_pad[HSP];
    __shared__ float red[4];
    __shared__ unsigned amLast;

    const int t = threadIdx.x;
    const int bid = blockIdx.x;
    const int b = bid >> 6;
    const int chunk = bid & 63;

    // ---- per-(batch,chunk) hard histogram, 1 float4 / thread ----
    if (t < BINS) lh[t] = 0u;
    __syncthreads();

    const float4* src = reinterpret_cast<const float4*>(
        y + (size_t)b * HW + (size_t)chunk * PIX_PER_BLOCK);
    float4 v = src[t];
    {
        float vals[4] = {v.x, v.y, v.z, v.w};
#pragma unroll
        for (int c = 0; c < 4; ++c) {
            int bin = (int)(vals[c] * 256.0f);
            bin = bin < 0 ? 0 : (bin > 255 ? 255 : bin);
            atomicAdd(&lh[bin], 1u);    // ds_add_u32
        }
    }
    __syncthreads();
    if (t < BINS) Hp[(size_t)bid * BINS + t] = lh[t];   // coalesced 1 KB
    __syncthreads();

    // ---- last-arriving block of this batch finalizes (no polling) ----
    if (t == 0) {
        __threadfence();                // make Hp stores agent-visible
        unsigned old = __hip_atomic_fetch_add(&ctrl[b], 1u,
                        __ATOMIC_ACQ_REL, __HIP_MEMORY_SCOPE_AGENT);
        amLast = (old == CHUNKS - 1) ? 1u : 0u;
    }
    __syncthreads();
    if (!amLast) return;
    __threadfence();                    // acquire side before reading peers' Hp

    const int bin = t & 255;
    const int g = t >> 8;               // 0..3

    // Reduce 64 chunk partials: group g sums 16 chunks (coalesced loads).
    float H = 0.0f;
    const unsigned* hb = Hp + ((size_t)(b * CHUNKS + g * 16) * BINS) + bin;
#pragma unroll
    for (int c = 0; c < 16; ++c) H += (float)hb[(size_t)c * BINS];
    Hs4[g][bin] = H;
    __syncthreads();

    // Zero-padded histogram (no edge branches in the conv).
    if (t < HSP) {
        float hv = 0.0f;
        int j = t - M_LO;
        if (j >= 0 && j < BINS)
            hv = Hs4[0][j] + Hs4[1][j] + Hs4[2][j] + Hs4[3][j];
        Hs_pad[t] = hv;
    }
    __syncthreads();

    // Truncated conv: hist[bin] = sum_{d=-64}^{63} k(d*DELTA) * Hs_pad[M_LO+bin+d].
    // Thread (bin,g) covers d = g*32-64+i. k computed in registers: shared-edge
    // sigmoids (k_i = s_{i+1} - s_i) -> 33 exps/thread, VALU overlaps DS reads.
    const float DELTA = 1.0f / 256.0f;
    const float SIGMA = 30.0f;
    const float base = (float)(g * GTAPS - M_LO) * DELTA;
    float acc = 0.0f;
    float s_prev = 1.0f / (1.0f + __expf(-SIGMA * (base - 0.5f * DELTA)));
    const float* hp = &Hs_pad[bin + g * GTAPS];  // [M_LO+bin+d] at i=0
#pragma unroll
    for (int i = 0; i < GTAPS; ++i) {
        float s_next = 1.0f / (1.0f + __expf(-SIGMA * (base + ((float)i + 0.5f) * DELTA)));
        acc = fmaf(s_next - s_prev, hp[i], acc);
        s_prev = s_next;
    }
    __syncthreads();
    Hs4[g][bin] = acc;                  // reuse as conv partials
    __syncthreads();

    // Entropy terms + block reduce.
    float e = 0.0f;
    if (t < BINS) {
        float hist = Hs4[0][t] + Hs4[1][t] + Hs4[2][t] + Hs4[3][t];
        float p = hist * (1.0f / (float)HW) + 1e-6f;
        e = -p * __logf(p);
    }
#pragma unroll
    for (int off = 32; off > 0; off >>= 1) e += __shfl_down(e, off);
    if (t < BINS && (t & 63) == 0) red[t >> 6] = e;
    __syncthreads();

    if (t == 0) {
        float part = red[0] + red[1] + red[2] + red[3];
        atomicAdd((float*)&ctrl[5], part);          // device-scope, zero-init'd
        __threadfence();
        unsigned old = __hip_atomic_fetch_add(&ctrl[4], 1u,
                        __ATOMIC_ACQ_REL, __HIP_MEMORY_SCOPE_AGENT);
        if (old == NB - 1) {                        // 4th finisher writes out
            float d = __hip_atomic_load((float*)&ctrl[5],
                        __ATOMIC_ACQUIRE, __HIP_MEMORY_SCOPE_AGENT);
            out[0] = 1.0f / d;
        }
    }
}

extern "C" void kernel_launch(void* const* d_in, const int* in_sizes, int n_in,
                              void* d_out, int out_size, void* d_ws, size_t ws_size,
                              hipStream_t stream) {
    const float* y = (const float*)d_in[0];
    unsigned* ctrl = (unsigned*)d_ws;
    unsigned* Hp = ctrl + 64;           // 256 B alignment for partials

    hipMemsetAsync(d_ws, 0, 64 * sizeof(unsigned), stream);   // zero ctrl only
    fused_entropy<<<HIST_BLOCKS, THREADS, 0, stream>>>(y, Hp, ctrl, (float*)d_out);
}

// Round 8
// 58.696 us; speedup vs baseline: 1.2910x; 1.2910x over previous
//
#include <hip/hip_runtime.h>
#include <math.h>

// Problem constants
#define NB 4
#define BINS 256
#define HW (512*512)

// Pass-1 decomposition (proven-best R5 shape)
#define CHUNKS 64                      // blocks per batch (256 blocks total = 1/CU)
#define PIX_PER_BLOCK (HW / CHUNKS)    // 4096
#define F4_PER_THREAD (PIX_PER_BLOCK / 4 / 256)  // 4

// Truncated correlation support d = m-j in [-64, 63]; tail kernel mass ~1e-3
// -> ~4e-5 abs output error vs 9.4e-4 threshold.
#define M_LO 64
#define TAPS 128
#define HSP (M_LO + BINS + M_LO)       // 384 zero-padded histogram entries

// ws layout: Hp[NB*CHUNKS*BINS] uint partial counts | acc(float) + cnt(uint)

// Pass 1: per-(batch,chunk) hard histogram partials. One LDS atomic per pixel.
// (unchanged from the 61.1 µs round-5 kernel)
__global__ __launch_bounds__(256) void hist_part(const float* __restrict__ y,
                                                 unsigned* __restrict__ Hp,
                                                 float* __restrict__ acc) {
    __shared__ unsigned lh[BINS];
    const int t = threadIdx.x;
    lh[t] = 0u;
    if (blockIdx.x == 0 && blockIdx.y == 0 && t == 0) {
        acc[0] = 0.0f;                       // entropy accumulator
        ((unsigned*)acc)[1] = 0u;            // completion counter
    }
    __syncthreads();

    const int b = blockIdx.y;
    const float4* src = reinterpret_cast<const float4*>(
        y + (size_t)b * HW + (size_t)blockIdx.x * PIX_PER_BLOCK);

#pragma unroll
    for (int i = 0; i < F4_PER_THREAD; ++i) {
        float4 v = src[t + 256 * i];
        float vals[4] = {v.x, v.y, v.z, v.w};
#pragma unroll
        for (int c = 0; c < 4; ++c) {
            int bin = (int)(vals[c] * 256.0f);
            bin = bin < 0 ? 0 : (bin > 255 ? 255 : bin);
            atomicAdd(&lh[bin], 1u);         // ds_add_u32, ~2-4-way contention
        }
    }
    __syncthreads();
    Hp[((size_t)b * CHUNKS + blockIdx.x) * BINS + t] = lh[t];  // coalesced
}

// Pass 2 (4 blocks = 1/batch): reduce chunk partials, build the 128-tap
// truncated kernel table (256 exps/block), correlate, entropy partial,
// last-finishing block writes 1/d.
__global__ __launch_bounds__(256) void entropy_fused(const unsigned* __restrict__ Hp,
                                                     float* __restrict__ acc,
                                                     float* __restrict__ out) {
    __shared__ float K0[TAPS];               // k((i-64)*DELTA), i=0..127
    __shared__ float Hs_pad[HSP];            // [64 zeros | 256 bins | 64 zeros]
    __shared__ float red[4];

    const int t = threadIdx.x;
    const int b = blockIdx.x;
    const float DELTA = 1.0f / 256.0f;
    const float SIGMA = 30.0f;

    // Zero pads.
    if (t < M_LO) Hs_pad[t] = 0.0f;
    if (t >= BINS - M_LO) Hs_pad[M_LO + BINS + (t - (BINS - M_LO))] = 0.0f;

    // Truncated kernel table: 128 entries, 2 exps each.
    if (t < TAPS) {
        float x = (float)(t - M_LO) * DELTA;             // c_m - c_j
        float sp = 1.0f / (1.0f + __expf(-SIGMA * (x + 0.5f * DELTA)));
        float sm = 1.0f / (1.0f + __expf(-SIGMA * (x - 0.5f * DELTA)));
        K0[t] = sp - sm;
    }

    // Reduce 64 chunk partials for bin t — fully coalesced (64 KB from L2).
    unsigned H = 0u;
    const unsigned* hb = Hp + (size_t)b * CHUNKS * BINS + t;
#pragma unroll 8
    for (int c = 0; c < CHUNKS; ++c) H += hb[c * BINS];
    Hs_pad[M_LO + t] = (float)H;
    __syncthreads();

    // 128-tap truncated correlation for output bin j = t:
    // hist[j] = sum_i K0[i] * Hs_pad[j + i]   (bin j+i-64)
    const int j = t;
    float hist = 0.0f;
#pragma unroll 8
    for (int i = 0; i < TAPS; ++i) {
        hist = fmaf(K0[i], Hs_pad[j + i], hist);   // broadcast + stride-1
    }

    float p = hist * (1.0f / (float)HW) + 1e-6f;
    float e = -p * __logf(p);

    // block-reduce 256 entropy terms
    const int lane = t & 63, wid = t >> 6;
#pragma unroll
    for (int off = 32; off > 0; off >>= 1) e += __shfl_down(e, off);
    if (lane == 0) red[wid] = e;
    __syncthreads();

    if (t == 0) {
        float part = red[0] + red[1] + red[2] + red[3];
        atomicAdd(acc, part);                        // device-scope
        __threadfence();
        unsigned old = atomicAdd(((unsigned*)acc) + 1, 1u);
        if (old == NB - 1) {                         // last block finishes
            __threadfence();
            float d = atomicAdd(acc, 0.0f);          // coherent read of total
            out[0] = 1.0f / d;
        }
    }
}

extern "C" void kernel_launch(void* const* d_in, const int* in_sizes, int n_in,
                              void* d_out, int out_size, void* d_ws, size_t ws_size,
                              hipStream_t stream) {
    const float* y = (const float*)d_in[0];
    unsigned* Hp = (unsigned*)d_ws;
    float* acc = (float*)(Hp + NB * CHUNKS * BINS);

    hist_part<<<dim3(CHUNKS, NB), 256, 0, stream>>>(y, Hp, acc);
    entropy_fused<<<NB, 256, 0, stream>>>(Hp, acc, (float*)d_out);
}

// Round 10
// 58.675 us; speedup vs baseline: 1.2914x; 1.0004x over previous
//
#include <hip/hip_runtime.h>
#include <math.h>

// Problem constants
#define NB 4
#define BINS 256
#define HW (512*512)

// Pass-1 decomposition: 256 blocks x 1024 threads -> 4 waves/SIMD per CU
// (vs 1 wave/SIMD at 256 threads; OccupancyPercent was pinned at ~8%).
#define CHUNKS 64                      // chunk blocks per batch
#define PIX_PER_BLOCK (HW / CHUNKS)    // 4096 = 1024 threads * 1 float4
#define HTHREADS 1024

// Truncated correlation support d = m-j in [-64, 63]; tail kernel mass ~1e-3
// -> ~4e-5 abs output error vs 9.4e-4 threshold.
#define M_LO 64
#define TAPS 128
#define HSP (M_LO + BINS + M_LO)       // 384 zero-padded histogram entries

// ws layout: Hp[NB*CHUNKS*BINS] uint partial counts | acc(float) + cnt(uint)

// Pass 1: per-(batch,chunk) hard histogram partials. One LDS atomic per pixel,
// one float4 load per thread.
__global__ __launch_bounds__(HTHREADS) void hist_part(const float* __restrict__ y,
                                                      unsigned* __restrict__ Hp,
                                                      float* __restrict__ acc) {
    __shared__ unsigned lh[BINS];
    const int t = threadIdx.x;
    if (t < BINS) lh[t] = 0u;
    if (blockIdx.x == 0 && blockIdx.y == 0 && t == 0) {
        acc[0] = 0.0f;                       // entropy accumulator
        ((unsigned*)acc)[1] = 0u;            // completion counter
    }
    __syncthreads();

    const int b = blockIdx.y;
    const float4* src = reinterpret_cast<const float4*>(
        y + (size_t)b * HW + (size_t)blockIdx.x * PIX_PER_BLOCK);

    float4 v = src[t];
    {
        float vals[4] = {v.x, v.y, v.z, v.w};
#pragma unroll
        for (int c = 0; c < 4; ++c) {
            int bin = (int)(vals[c] * 256.0f);
            bin = bin < 0 ? 0 : (bin > 255 ? 255 : bin);
            atomicAdd(&lh[bin], 1u);         // ds_add_u32, ~2-way bank aliasing
        }
    }
    __syncthreads();
    if (t < BINS)
        Hp[((size_t)b * CHUNKS + blockIdx.x) * BINS + t] = lh[t];  // coalesced
}

// Pass 2 (4 blocks = 1/batch): reduce chunk partials, build the 128-tap
// truncated kernel table (256 exps/block), correlate, entropy partial,
// last-finishing block writes 1/d.  (unchanged from the 58.7 µs round-8)
__global__ __launch_bounds__(256) void entropy_fused(const unsigned* __restrict__ Hp,
                                                     float* __restrict__ acc,
                                                     float* __restrict__ out) {
    __shared__ float K0[TAPS];               // k((i-64)*DELTA), i=0..127
    __shared__ float Hs_pad[HSP];            // [64 zeros | 256 bins | 64 zeros]
    __shared__ float red[4];

    const int t = threadIdx.x;
    const int b = blockIdx.x;
    const float DELTA = 1.0f / 256.0f;
    const float SIGMA = 30.0f;

    // Zero pads.
    if (t < M_LO) Hs_pad[t] = 0.0f;
    if (t >= BINS - M_LO) Hs_pad[M_LO + BINS + (t - (BINS - M_LO))] = 0.0f;

    // Truncated kernel table: 128 entries, 2 exps each.
    if (t < TAPS) {
        float x = (float)(t - M_LO) * DELTA;             // c_m - c_j
        float sp = 1.0f / (1.0f + __expf(-SIGMA * (x + 0.5f * DELTA)));
        float sm = 1.0f / (1.0f + __expf(-SIGMA * (x - 0.5f * DELTA)));
        K0[t] = sp - sm;
    }

    // Reduce 64 chunk partials for bin t — fully coalesced (64 KB from L2).
    unsigned H = 0u;
    const unsigned* hb = Hp + (size_t)b * CHUNKS * BINS + t;
#pragma unroll 8
    for (int c = 0; c < CHUNKS; ++c) H += hb[c * BINS];
    Hs_pad[M_LO + t] = (float)H;
    __syncthreads();

    // 128-tap truncated correlation for output bin j = t:
    // hist[j] = sum_i K0[i] * Hs_pad[j + i]   (bin j+i-64)
    const int j = t;
    float hist = 0.0f;
#pragma unroll 8
    for (int i = 0; i < TAPS; ++i) {
        hist = fmaf(K0[i], Hs_pad[j + i], hist);   // broadcast + stride-1
    }

    float p = hist * (1.0f / (float)HW) + 1e-6f;
    float e = -p * __logf(p);

    // block-reduce 256 entropy terms
    const int lane = t & 63, wid = t >> 6;
#pragma unroll
    for (int off = 32; off > 0; off >>= 1) e += __shfl_down(e, off);
    if (lane == 0) red[wid] = e;
    __syncthreads();

    if (t == 0) {
        float part = red[0] + red[1] + red[2] + red[3];
        atomicAdd(acc, part);                        // device-scope
        __threadfence();
        unsigned old = atomicAdd(((unsigned*)acc) + 1, 1u);
        if (old == NB - 1) {                         // last block finishes
            __threadfence();
            float d = atomicAdd(acc, 0.0f);          // coherent read of total
            out[0] = 1.0f / d;
        }
    }
}

extern "C" void kernel_launch(void* const* d_in, const int* in_sizes, int n_in,
                              void* d_out, int out_size, void* d_ws, size_t ws_size,
                              hipStream_t stream) {
    const float* y = (const float*)d_in[0];
    unsigned* Hp = (unsigned*)d_ws;
    float* acc = (float*)(Hp + NB * CHUNKS * BINS);

    hist_part<<<dim3(CHUNKS, NB), HTHREADS, 0, stream>>>(y, Hp, acc);
    entropy_fused<<<NB, 256, 0, stream>>>(Hp, acc, (float*)d_out);
}